// Round 2
// baseline (327.593 us; speedup 1.0000x reference)
//
#include <hip/hip_runtime.h>

#define N_NODES 500000
#define K_NB 16
#define F_IN 7
#define F_HID 40
#define F_OUT 3

// Thread-per-node. Layer-2 commuted past the k-mean:
//   y = (sum_k relu(m_k@W1 + b1)) @ W2 / 16 + b2
// W1 packed transposed in LDS as [h][8] = {W1[0..6][h], b1[h]} -> two b128 broadcast reads per h.
// W2 packed as [h][4] = {W2[h][0..2], 0} -> one b128 broadcast read per h.
// Mailbox kept in a plain float[112] register array with all-constant indices
// (NO pointer casts -> SROA promotes it; the round-1 (float*)cast sent it to scratch).
__global__ __launch_bounds__(256) void aggre_kernel(
    const float* __restrict__ mailbox,
    const float* __restrict__ W1,
    const float* __restrict__ b1,
    const float* __restrict__ W2,
    const float* __restrict__ b2,
    float* __restrict__ out)
{
    __shared__ float4 w1lds[F_HID * 2];  // [h*2+0] = W1[0..3][h]; [h*2+1] = {W1[4..6][h], b1[h]}
    __shared__ float4 w2lds[F_HID];      // [h] = {W2[h][0..2], 0}

    const int t = threadIdx.x;
    if (t < F_HID * 2) {          // 80 threads fill w1lds
        const int h = t >> 1;
        float4 v;
        if ((t & 1) == 0) {
            v.x = W1[0 * F_HID + h]; v.y = W1[1 * F_HID + h];
            v.z = W1[2 * F_HID + h]; v.w = W1[3 * F_HID + h];
        } else {
            v.x = W1[4 * F_HID + h]; v.y = W1[5 * F_HID + h];
            v.z = W1[6 * F_HID + h]; v.w = b1[h];
        }
        w1lds[t] = v;
    } else if (t < F_HID * 2 + F_HID) {  // 40 threads fill w2lds
        const int h = t - F_HID * 2;
        float4 v;
        v.x = W2[h * F_OUT + 0];
        v.y = W2[h * F_OUT + 1];
        v.z = W2[h * F_OUT + 2];
        v.w = 0.0f;
        w2lds[h] = v;
    }
    __syncthreads();

    const int n = blockIdx.x * blockDim.x + threadIdx.x;
    if (n >= N_NODES) return;

    // Load this node's 16x7 mailbox block: 112 floats = 28 float4 (448 B, 16B-aligned),
    // then scatter into a scalar register array with constant indices only.
    const float4* __restrict__ src =
        (const float4*)(mailbox + (size_t)n * (K_NB * F_IN));
    float m[K_NB * F_IN];
    #pragma unroll
    for (int i = 0; i < 28; ++i) {
        const float4 v = src[i];
        m[4 * i + 0] = v.x;
        m[4 * i + 1] = v.y;
        m[4 * i + 2] = v.z;
        m[4 * i + 3] = v.w;
    }

    float a0 = 0.0f, a1 = 0.0f, a2 = 0.0f;

    for (int h = 0; h < F_HID; ++h) {
        const float4 wa = w1lds[h * 2 + 0];
        const float4 wb = w1lds[h * 2 + 1];  // wb.w = b1[h]
        float sh = 0.0f;
        #pragma unroll
        for (int k = 0; k < K_NB; ++k) {
            float acc = wb.w;
            acc = fmaf(m[k * F_IN + 0], wa.x, acc);
            acc = fmaf(m[k * F_IN + 1], wa.y, acc);
            acc = fmaf(m[k * F_IN + 2], wa.z, acc);
            acc = fmaf(m[k * F_IN + 3], wa.w, acc);
            acc = fmaf(m[k * F_IN + 4], wb.x, acc);
            acc = fmaf(m[k * F_IN + 5], wb.y, acc);
            acc = fmaf(m[k * F_IN + 6], wb.z, acc);
            sh += fmaxf(acc, 0.0f);
        }
        const float4 w2v = w2lds[h];
        a0 = fmaf(sh, w2v.x, a0);
        a1 = fmaf(sh, w2v.y, a1);
        a2 = fmaf(sh, w2v.z, a2);
    }

    const float inv = 1.0f / (float)K_NB;
    float* __restrict__ op = out + (size_t)n * F_OUT;
    op[0] = fmaf(a0, inv, b2[0]);
    op[1] = fmaf(a1, inv, b2[1]);
    op[2] = fmaf(a2, inv, b2[2]);
}

extern "C" void kernel_launch(void* const* d_in, const int* in_sizes, int n_in,
                              void* d_out, int out_size, void* d_ws, size_t ws_size,
                              hipStream_t stream) {
    const float* mailbox = (const float*)d_in[0];
    const float* W1      = (const float*)d_in[1];
    const float* b1      = (const float*)d_in[2];
    const float* W2      = (const float*)d_in[3];
    const float* b2      = (const float*)d_in[4];
    float* out = (float*)d_out;

    const int threads = 256;
    const int blocks = (N_NODES + threads - 1) / threads;
    aggre_kernel<<<blocks, threads, 0, stream>>>(mailbox, W1, b1, W2, b2, out);
}

// Round 3
// 315.416 us; speedup vs baseline: 1.0386x; 1.0386x over previous
//
#include <hip/hip_runtime.h>
#include <stdint.h>

#define N_NODES 500000
#define K_NB 16
#define F_IN 7
#define F_HID 40
#define F_OUT 3
#define NODE_FLOATS (K_NB * F_IN)   // 112 floats = 28 float4 per node
#define NPW 16                      // nodes per wave-tile (500000 % 16 == 0 -> no partial tiles)
#define WPB 4                       // waves per block (block = 256)
#define NPB (NPW * WPB)             // 64 nodes per block

typedef __attribute__((address_space(3))) void lds_void_t;
typedef __attribute__((address_space(1))) const void glb_void_t;

// Coalesced-load restructure:
//  - wave stages 16 nodes (7168 B) via 7x global_load_lds_dwordx4: lane l step j
//    fetches global float4 (tile_base*28 + j*64 + l) -> pure linear, 1KB/instr.
//    (round-1/2 kernels did per-thread 448B-strided dwordx4: 64 distinct cache
//     lines per instruction -> TA/L1 address serialization, est ~90us.)
//  - 4 lanes per node: lane r takes k in {4r..4r+3} = 28 contiguous floats,
//    7x ds_read_b128 (start banks cover all 8 four-bank groups -> structural min),
//    kept in VGPRs for the whole h loop.
//  - layer 2 commuted past the k-mean; applied per-lane (linear), quad-reduced
//    with __shfl_xor at the end.
__global__ __launch_bounds__(256) void aggre_kernel(
    const float* __restrict__ mailbox,
    const float* __restrict__ W1,
    const float* __restrict__ b1,
    const float* __restrict__ W2,
    const float* __restrict__ b2,
    float* __restrict__ out)
{
    __shared__ float4 w1lds[F_HID * 2];  // [h*2+0]=W1[0..3][h]; [h*2+1]={W1[4..6][h], b1[h]}
    __shared__ float4 w2lds[F_HID];      // [h]={W2[h][0..2], 0}
    __shared__ __align__(16) float tile[WPB][NPW * NODE_FLOATS];  // 4 x 7168 B

    const int t = threadIdx.x;
    if (t < F_HID * 2) {
        const int h = t >> 1;
        float4 v;
        if ((t & 1) == 0) {
            v.x = W1[0 * F_HID + h]; v.y = W1[1 * F_HID + h];
            v.z = W1[2 * F_HID + h]; v.w = W1[3 * F_HID + h];
        } else {
            v.x = W1[4 * F_HID + h]; v.y = W1[5 * F_HID + h];
            v.z = W1[6 * F_HID + h]; v.w = b1[h];
        }
        w1lds[t] = v;
    } else if (t < F_HID * 3) {
        const int h = t - F_HID * 2;
        float4 v;
        v.x = W2[h * F_OUT + 0];
        v.y = W2[h * F_OUT + 1];
        v.z = W2[h * F_OUT + 2];
        v.w = 0.0f;
        w2lds[h] = v;
    }
    __syncthreads();

    const int wave = t >> 6;
    const int lane = t & 63;
    const long tile0 = (long)blockIdx.x * NPB + (long)wave * NPW;  // first node of wave-tile
    if (tile0 >= N_NODES) return;  // whole-wave uniform; after the only barrier

    // ---- stage 16 nodes, coalesced, direct-to-LDS ----
    const float* gsrc = mailbox + (size_t)tile0 * NODE_FLOATS;
    #pragma unroll
    for (int j = 0; j < 7; ++j) {
        const float* g = gsrc + (size_t)(j * 64 + lane) * 4;
        __builtin_amdgcn_global_load_lds(
            (glb_void_t*)g,
            (lds_void_t*)&tile[wave][j * 256],
            16, 0, 0);
    }
    __builtin_amdgcn_s_waitcnt(0x0f70);  // vmcnt(0); expcnt/lgkmcnt masked off

    // ---- per-quad compute: lane r of node nloc handles k = 4r..4r+3 ----
    const int nloc = lane >> 2;
    const int r = lane & 3;
    const float* mp = &tile[wave][nloc * NODE_FLOATS + r * 28];
    float m[28];
    #pragma unroll
    for (int i = 0; i < 7; ++i) {
        const float4 v = ((const float4*)mp)[i];
        m[4 * i + 0] = v.x; m[4 * i + 1] = v.y;
        m[4 * i + 2] = v.z; m[4 * i + 3] = v.w;
    }

    float a0 = 0.0f, a1 = 0.0f, a2 = 0.0f;
    #pragma unroll 2
    for (int h = 0; h < F_HID; ++h) {
        const float4 wa = w1lds[2 * h + 0];   // broadcast ds_read (all lanes same addr)
        const float4 wb = w1lds[2 * h + 1];   // wb.w = b1[h]
        float sh = 0.0f;
        #pragma unroll
        for (int kk = 0; kk < 4; ++kk) {
            const int o = kk * F_IN;
            float acc = wb.w;
            acc = fmaf(m[o + 0], wa.x, acc);
            acc = fmaf(m[o + 1], wa.y, acc);
            acc = fmaf(m[o + 2], wa.z, acc);
            acc = fmaf(m[o + 3], wa.w, acc);
            acc = fmaf(m[o + 4], wb.x, acc);
            acc = fmaf(m[o + 5], wb.y, acc);
            acc = fmaf(m[o + 6], wb.z, acc);
            sh += fmaxf(acc, 0.0f);
        }
        const float4 w2v = w2lds[h];
        a0 = fmaf(sh, w2v.x, a0);
        a1 = fmaf(sh, w2v.y, a1);
        a2 = fmaf(sh, w2v.z, a2);
    }

    // ---- reduce the 4 k-partials within each quad ----
    a0 += __shfl_xor(a0, 1); a0 += __shfl_xor(a0, 2);
    a1 += __shfl_xor(a1, 1); a1 += __shfl_xor(a1, 2);
    a2 += __shfl_xor(a2, 1); a2 += __shfl_xor(a2, 2);

    if (r < F_OUT) {
        const float val = (r == 0) ? a0 : ((r == 1) ? a1 : a2);
        out[(size_t)(tile0 + nloc) * F_OUT + r] =
            fmaf(val, 1.0f / (float)K_NB, b2[r]);
    }
}

extern "C" void kernel_launch(void* const* d_in, const int* in_sizes, int n_in,
                              void* d_out, int out_size, void* d_ws, size_t ws_size,
                              hipStream_t stream) {
    const float* mailbox = (const float*)d_in[0];
    const float* W1      = (const float*)d_in[1];
    const float* b1      = (const float*)d_in[2];
    const float* W2      = (const float*)d_in[3];
    const float* b2      = (const float*)d_in[4];
    float* out = (float*)d_out;

    const int blocks = (N_NODES + NPB - 1) / NPB;  // 7813
    aggre_kernel<<<blocks, 256, 0, stream>>>(mailbox, W1, b1, W2, b2, out);
}